// Round 6
// baseline (72.401 us; speedup 1.0000x reference)
//
#include <hip/hip_runtime.h>

#define BB 16
#define SS 16
#define LL 128
#define DD 768
#define AA 8
#define TT 8
#define PAD_ID 1
#define NARG 24          // 3 arg types * 8 args
#define NROW 25          // 1 mean row + 24 arg rows
#define NT 384           // 6 waves; 384 threads x 2 cols = 768 = D
#define CH 8             // L-rows per software-pipeline stage

__global__ __launch_bounds__(NT) void srl_kernel(
    const int* __restrict__ sid_g,
    const int* __restrict__ mask_g,
    const float* __restrict__ emb_g,
    const int* __restrict__ pred_g,
    const int* __restrict__ a0_g,
    const int* __restrict__ a1_g,
    float* __restrict__ out)
{
    __shared__ int   sid[LL];
    __shared__ float maskf[LL];
    __shared__ float Wt[NROW][LL];      // transposed: row r, position l
    __shared__ float coeff[NARG][TT];
    __shared__ float validf[NARG][TT];
    __shared__ int   toks[NARG][TT];
    __shared__ float inv_msum;
    __shared__ int   amask_sh;          // bit j set <=> arg row j+1 has any weight

    const int bs  = blockIdx.x;
    const int tid = threadIdx.x;

    // ---- Phase A: stage sentence ids + mask ----
    if (tid < LL) {
        sid[tid]   = sid_g[bs * LL + tid];
        maskf[tid] = (float)mask_g[bs * LL + tid];
    }
    if (tid == NT - 1) amask_sh = 0;
    __syncthreads();

    // ---- Phase B1: per-token match count + valid (threads 0..191),
    //      mask-sum reduction on wave 5 (threads 320..383) ----
    if (tid < NARG * TT) {
        const int j = tid >> 3;         // arg index 0..23
        const int t = tid & 7;          // token index
        const int k = j >> 3;           // arg type 0..2
        const int a = j & 7;            // arg slot
        const int* src = (k == 0) ? pred_g : (k == 1) ? a0_g : a1_g;
        const int tok = src[bs * AA * TT + a * TT + t];
        int cnt = 0;
        for (int l = 0; l < LL; ++l) cnt += (sid[l] == tok) ? 1 : 0;
        const float v = (tok != PAD_ID) ? 1.0f : 0.0f;
        toks[j][t]   = tok;
        validf[j][t] = v;
        coeff[j][t]  = v / (float)(cnt > 1 ? cnt : 1);
        if (v != 0.0f && cnt > 0) atomicOr(&amask_sh, 1 << j);
    } else if (tid >= 320) {
        const int lane = tid - 320;     // lanes of wave 5
        float s = maskf[lane] + maskf[lane + 64];
        for (int off = 32; off; off >>= 1) s += __shfl_xor(s, off, 64);
        if (lane == 0) inv_msum = 1.0f / fmaxf(s, 1.0f);
    }
    __syncthreads();

    // ---- Phase B2: fold 1/n_valid into coefficients ----
    if (tid < NARG) {
        float nv = 0.0f;
        #pragma unroll
        for (int t = 0; t < TT; ++t) nv += validf[tid][t];
        const float inv = 1.0f / fmaxf(nv, 1.0f);
        #pragma unroll
        for (int t = 0; t < TT; ++t) coeff[tid][t] *= inv;
    }
    __syncthreads();

    // ---- Phase C: materialize Wt[r][l] ----
    for (int idx = tid; idx < NROW * LL; idx += NT) {
        const int r = idx >> 7;         // 0..24
        const int l = idx & (LL - 1);
        float w;
        if (r == 0) {
            w = maskf[l] * inv_msum;
        } else {
            const int j  = r - 1;
            const int sl = sid[l];
            w = 0.0f;
            #pragma unroll
            for (int t = 0; t < TT; ++t)
                w += (sl == toks[j][t]) ? coeff[j][t] : 0.0f;
        }
        Wt[r][l] = w;
    }
    __syncthreads();

    // ---- Phase D: sparse-row weighted reduction, 2 cols per thread ----
    const int amask = amask_sh;         // block-uniform
    const int col = tid * 2;
    const float* ep = emb_g + (size_t)bs * (LL * DD) + col;
    float* out0 = out;                               // [B*S, D]
    float* outA = out + (size_t)BB * SS * DD;        // 3 x [B*S, A, D]

    // zero inactive arg rows
    #pragma unroll
    for (int j = 0; j < NARG; ++j) {
        if (!((amask >> j) & 1)) {
            float2 z = make_float2(0.0f, 0.0f);
            *reinterpret_cast<float2*>(
                &outA[(size_t)(j >> 3) * (BB * SS * AA * DD) +
                      ((size_t)bs * AA + (j & 7)) * DD + col]) = z;
        }
    }

    // first two active rows (if any) fused with row 0 in one E sweep
    int r1j = -1, r2j = -1;
    {
        int m = amask;
        if (m) { r1j = __ffs(m) - 1; m &= m - 1; if (m) r2j = __ffs(m) - 1; }
    }
    const int c1 = (r1j >= 0) ? r1j + 1 : 0;
    const int c2 = (r2j >= 0) ? r2j + 1 : 0;

    float2 a0 = make_float2(0.0f, 0.0f);
    float2 aA = make_float2(0.0f, 0.0f);
    float2 aB = make_float2(0.0f, 0.0f);
    {
        float2 cur[CH], nxt[CH];
        #pragma unroll
        for (int j = 0; j < CH; ++j)
            cur[j] = *reinterpret_cast<const float2*>(&ep[(size_t)j * DD]);
        for (int l0 = 0; l0 < LL; l0 += CH) {
            if (l0 + CH < LL) {
                #pragma unroll
                for (int j = 0; j < CH; ++j)
                    nxt[j] = *reinterpret_cast<const float2*>(&ep[(size_t)(l0 + CH + j) * DD]);
            }
            #pragma unroll
            for (int j = 0; j < CH; ++j) {
                const float w0 = Wt[0][l0 + j];
                const float wa = Wt[c1][l0 + j];
                const float wb = Wt[c2][l0 + j];
                const float2 e = cur[j];
                a0.x += w0 * e.x;  a0.y += w0 * e.y;
                aA.x += wa * e.x;  aA.y += wa * e.y;
                aB.x += wb * e.x;  aB.y += wb * e.y;
            }
            #pragma unroll
            for (int j = 0; j < CH; ++j) cur[j] = nxt[j];
        }
    }
    *reinterpret_cast<float2*>(&out0[(size_t)bs * DD + col]) = a0;
    if (r1j >= 0)
        *reinterpret_cast<float2*>(
            &outA[(size_t)(r1j >> 3) * (BB * SS * AA * DD) +
                  ((size_t)bs * AA + (r1j & 7)) * DD + col]) = aA;
    if (r2j >= 0)
        *reinterpret_cast<float2*>(
            &outA[(size_t)(r2j >> 3) * (BB * SS * AA * DD) +
                  ((size_t)bs * AA + (r2j & 7)) * DD + col]) = aB;

    // rare: more than two active rows -> one extra E sweep per row
    int m = amask;
    if (r1j >= 0) m &= ~(1 << r1j);
    if (r2j >= 0) m &= ~(1 << r2j);
    while (m) {
        const int j = __ffs(m) - 1;
        m &= m - 1;
        const int c = j + 1;
        float2 acc = make_float2(0.0f, 0.0f);
        float2 cur[CH], nxt[CH];
        #pragma unroll
        for (int q = 0; q < CH; ++q)
            cur[q] = *reinterpret_cast<const float2*>(&ep[(size_t)q * DD]);
        for (int l0 = 0; l0 < LL; l0 += CH) {
            if (l0 + CH < LL) {
                #pragma unroll
                for (int q = 0; q < CH; ++q)
                    nxt[q] = *reinterpret_cast<const float2*>(&ep[(size_t)(l0 + CH + q) * DD]);
            }
            #pragma unroll
            for (int q = 0; q < CH; ++q) {
                const float w = Wt[c][l0 + q];
                acc.x += w * cur[q].x;  acc.y += w * cur[q].y;
            }
            #pragma unroll
            for (int q = 0; q < CH; ++q) cur[q] = nxt[q];
        }
        *reinterpret_cast<float2*>(
            &outA[(size_t)(j >> 3) * (BB * SS * AA * DD) +
                  ((size_t)bs * AA + (j & 7)) * DD + col]) = acc;
    }
}

extern "C" void kernel_launch(void* const* d_in, const int* in_sizes, int n_in,
                              void* d_out, int out_size, void* d_ws, size_t ws_size,
                              hipStream_t stream) {
    const int*   sid  = (const int*)d_in[0];
    const int*   mask = (const int*)d_in[1];
    const float* emb  = (const float*)d_in[2];
    const int*   pred = (const int*)d_in[3];
    const int*   a0   = (const int*)d_in[4];
    const int*   a1   = (const int*)d_in[5];
    float* outp = (float*)d_out;

    srl_kernel<<<dim3(BB * SS), dim3(NT), 0, stream>>>(sid, mask, emb, pred, a0, a1, outp);
}

// Round 7
// 32.541 us; speedup vs baseline: 2.2249x; 2.2249x over previous
//
#include <hip/hip_runtime.h>

#define BB 16
#define SS 16
#define LL 128
#define DD 768
#define AA 8
#define TT 8
#define PAD_ID 1
#define NARG 24          // 3 arg types * 8 args
#define NT 1024          // 16 waves: 4 L-segments x 256 cols
#define NCOL 256         // cols per block
#define NSEG 4           // in-block L split
#define SEGL 32          // LL / NSEG
#define CH 8             // rows per software-pipeline stage

__global__ __launch_bounds__(NT) void srl_kernel(
    const int* __restrict__ sid_g,
    const int* __restrict__ mask_g,
    const float* __restrict__ emb_g,
    const int* __restrict__ pred_g,
    const int* __restrict__ a0_g,
    const int* __restrict__ a1_g,
    float* __restrict__ out)
{
    __shared__ int   sid[LL];
    __shared__ float maskf[LL];
    __shared__ float Wt4[LL][4];        // slot-packed weights (slot0=mean row)
    __shared__ float coeff[NARG][TT];
    __shared__ float validf[NARG][TT];
    __shared__ int   toks[NARG][TT];
    __shared__ float inv_msum;
    __shared__ int   amask_sh;
    __shared__ int   nact_sh;
    __shared__ int   actlist[NARG];
    __shared__ float P[NSEG][NCOL][4];  // cross-segment partials (16 KB)
    __shared__ float Wx[LL];            // weights for rare extra rows

    const int bs   = blockIdx.x;
    const int cc   = blockIdx.y;
    const int tid  = threadIdx.x;
    const int col  = tid & (NCOL - 1);
    const int seg  = tid >> 8;          // 0..3
    const int gcol = cc * NCOL + col;

    float* out0 = out;                               // [B*S, D]
    float* outA = out + (size_t)BB * SS * DD;        // 3 x [B*S, A, D]

    // ---- Phase A: stage sentence ids + mask ----
    if (tid < LL) {
        sid[tid]   = sid_g[bs * LL + tid];
        maskf[tid] = (float)mask_g[bs * LL + tid];
    }
    if (tid == 0) amask_sh = 0;
    __syncthreads();

    // ---- Phase B1: per-token match count + valid (threads 0..191),
    //      mask-sum on wave 5 (threads 320..383) ----
    if (tid < NARG * TT) {
        const int j = tid >> 3;
        const int t = tid & 7;
        const int k = j >> 3;
        const int a = j & 7;
        const int* src = (k == 0) ? pred_g : (k == 1) ? a0_g : a1_g;
        const int tok = src[bs * AA * TT + a * TT + t];
        int cnt = 0;
        for (int l = 0; l < LL; ++l) cnt += (sid[l] == tok) ? 1 : 0;
        const float v = (tok != PAD_ID) ? 1.0f : 0.0f;
        toks[j][t]   = tok;
        validf[j][t] = v;
        coeff[j][t]  = v / (float)(cnt > 1 ? cnt : 1);
        if (v != 0.0f && cnt > 0) atomicOr(&amask_sh, 1 << j);
    } else if (tid >= 320 && tid < 384) {
        const int lane = tid - 320;
        float s = maskf[lane] + maskf[lane + 64];
        for (int off = 32; off; off >>= 1) s += __shfl_xor(s, off, 64);
        if (lane == 0) inv_msum = 1.0f / fmaxf(s, 1.0f);
    }
    __syncthreads();

    // ---- Phase B2: fold 1/n_valid; build active-row list ----
    if (tid < NARG) {
        float nv = 0.0f;
        #pragma unroll
        for (int t = 0; t < TT; ++t) nv += validf[tid][t];
        const float inv = 1.0f / fmaxf(nv, 1.0f);
        #pragma unroll
        for (int t = 0; t < TT; ++t) coeff[tid][t] *= inv;
    } else if (tid == NARG) {
        int n = 0;
        const int m = amask_sh;
        for (int j = 0; j < NARG; ++j) if ((m >> j) & 1) actlist[n++] = j;
        nact_sh = n;
        for (int s = n; s < NARG; ++s) actlist[s] = -1;
    }
    __syncthreads();

    // ---- Phase C: slot-packed weights (threads 0..511);
    //      zero-fill inactive rows (threads 768..1023) ----
    if (tid < LL * 4) {
        const int l = tid >> 2;
        const int s = tid & 3;
        float w = 0.0f;
        if (s == 0) {
            w = maskf[l] * inv_msum;
        } else {
            const int j = actlist[s - 1];
            if (j >= 0) {
                const int sl = sid[l];
                #pragma unroll
                for (int t = 0; t < TT; ++t)
                    w += (sl == toks[j][t]) ? coeff[j][t] : 0.0f;
            }
        }
        Wt4[l][s] = w;
    } else if (tid >= 768) {
        const int m = amask_sh;
        #pragma unroll
        for (int j = 0; j < NARG; ++j) {
            if (!((m >> j) & 1)) {
                outA[(size_t)(j >> 3) * (BB * SS * AA * DD) +
                     ((size_t)bs * AA + (j & 7)) * DD + gcol] = 0.0f;
            }
        }
    }
    __syncthreads();

    // ---- Phase D: each thread sweeps its 32-row segment, 1 col ----
    const float* ep = emb_g + (size_t)bs * (LL * DD) + (size_t)(seg * SEGL) * DD + gcol;

    float a0 = 0.0f, a1 = 0.0f, a2 = 0.0f, a3 = 0.0f;
    {
        float cur[CH], nxt[CH];
        #pragma unroll
        for (int q = 0; q < CH; ++q) cur[q] = ep[(size_t)q * DD];
        #pragma unroll
        for (int l0 = 0; l0 < SEGL; l0 += CH) {
            if (l0 + CH < SEGL) {
                #pragma unroll
                for (int q = 0; q < CH; ++q)
                    nxt[q] = ep[(size_t)(l0 + CH + q) * DD];
            }
            #pragma unroll
            for (int q = 0; q < CH; ++q) {
                const float4 w = *reinterpret_cast<const float4*>(&Wt4[seg * SEGL + l0 + q][0]);
                const float e = cur[q];
                a0 += w.x * e;  a1 += w.y * e;  a2 += w.z * e;  a3 += w.w * e;
            }
            #pragma unroll
            for (int q = 0; q < CH; ++q) cur[q] = nxt[q];
        }
    }
    *reinterpret_cast<float4*>(&P[seg][col][0]) = make_float4(a0, a1, a2, a3);
    __syncthreads();

    // ---- Combine across segments; store ----
    {
        const int slot = seg;           // thread (slot, col)
        const float s = P[0][col][slot] + P[1][col][slot]
                      + P[2][col][slot] + P[3][col][slot];
        if (slot == 0) {
            out0[(size_t)bs * DD + gcol] = s;
        } else if (slot - 1 < nact_sh) {
            const int j = actlist[slot - 1];
            outA[(size_t)(j >> 3) * (BB * SS * AA * DD) +
                 ((size_t)bs * AA + (j & 7)) * DD + gcol] = s;
        }
    }

    // ---- Rare: more than 3 active rows -> extra block-uniform sweeps ----
    for (int e = 3; e < nact_sh; ++e) {
        const int je = actlist[e];
        __syncthreads();                // P, Wx free for reuse
        if (tid < LL) {
            const int sl = sid[tid];
            float w = 0.0f;
            #pragma unroll
            for (int t = 0; t < TT; ++t)
                w += (sl == toks[je][t]) ? coeff[je][t] : 0.0f;
            Wx[tid] = w;
        }
        __syncthreads();
        float acc = 0.0f;
        for (int l = 0; l < SEGL; ++l)
            acc += Wx[seg * SEGL + l] * ep[(size_t)l * DD];
        P[seg][col][0] = acc;
        __syncthreads();
        if (seg == 0) {
            const float s = P[0][col][0] + P[1][col][0]
                          + P[2][col][0] + P[3][col][0];
            outA[(size_t)(je >> 3) * (BB * SS * AA * DD) +
                 ((size_t)bs * AA + (je & 7)) * DD + gcol] = s;
        }
    }
}

extern "C" void kernel_launch(void* const* d_in, const int* in_sizes, int n_in,
                              void* d_out, int out_size, void* d_ws, size_t ws_size,
                              hipStream_t stream) {
    const int*   sid  = (const int*)d_in[0];
    const int*   mask = (const int*)d_in[1];
    const float* emb  = (const float*)d_in[2];
    const int*   pred = (const int*)d_in[3];
    const int*   a0   = (const int*)d_in[4];
    const int*   a1   = (const int*)d_in[5];
    float* outp = (float*)d_out;

    srl_kernel<<<dim3(BB * SS, DD / NCOL), dim3(NT), 0, stream>>>(
        sid, mask, emb, pred, a0, a1, outp);
}

// Round 8
// 30.685 us; speedup vs baseline: 2.3595x; 1.0605x over previous
//
#include <hip/hip_runtime.h>

#define BB 16
#define SS 16
#define LL 128
#define DD 768
#define AA 8
#define TT 8
#define PAD_ID 1
#define NARG 24          // 3 arg types * 8 args
#define NT 768           // 12 waves
#define NQ 96            // float4 col-quads per block (384 cols)
#define NSEG 8           // in-block L split
#define SEGL 16          // LL / NSEG
#define CH 4             // rows per pipeline stage
#define COLS 384         // cols per block

__global__ __launch_bounds__(NT) void srl_kernel(
    const int* __restrict__ sid_g,
    const int* __restrict__ mask_g,
    const float* __restrict__ emb_g,
    const int* __restrict__ pred_g,
    const int* __restrict__ a0_g,
    const int* __restrict__ a1_g,
    float* __restrict__ out)
{
    __shared__ int    sid[LL];
    __shared__ float  maskf[LL];
    __shared__ float  Wt4[LL][4];       // slot-packed weights (slot0 = mean row)
    __shared__ float  coeff[NARG][TT];
    __shared__ float  validf[NARG][TT];
    __shared__ int    toks[NARG][TT];
    __shared__ float  inv_msum;
    __shared__ int    amask_sh;
    __shared__ int    nact_sh;
    __shared__ int    actlist[NARG];
    __shared__ int    slotmap[NARG];    // row j -> slot 1..3, or -1
    __shared__ float4 P4[NSEG][NQ][4];  // cross-segment partials (48 KB)
    __shared__ float  Wx[LL];           // weights for rare extra rows

    const int bs  = blockIdx.x;
    const int cc  = blockIdx.y;
    const int tid = threadIdx.x;
    const int q   = tid % NQ;           // col-quad within block
    const int seg = tid / NQ;           // 0..7

    float* out0 = out;                               // [B*S, D]
    float* outA = out + (size_t)BB * SS * DD;        // 3 x [B*S, A, D]
    const int colbase = cc * COLS + 4 * q;

    // ---- Phase A: stage sentence ids + mask ----
    if (tid < LL) {
        sid[tid]   = sid_g[bs * LL + tid];
        maskf[tid] = (float)mask_g[bs * LL + tid];
    }
    if (tid == 0) amask_sh = 0;
    __syncthreads();

    // ---- Phase B1: per-token match count + valid (threads 0..191),
    //      mask-sum on threads 320..383 ----
    if (tid < NARG * TT) {
        const int j = tid >> 3;
        const int t = tid & 7;
        const int k = j >> 3;
        const int a = j & 7;
        const int* src = (k == 0) ? pred_g : (k == 1) ? a0_g : a1_g;
        const int tok = src[bs * AA * TT + a * TT + t];
        int cnt = 0;
        for (int l = 0; l < LL; ++l) cnt += (sid[l] == tok) ? 1 : 0;
        const float v = (tok != PAD_ID) ? 1.0f : 0.0f;
        toks[j][t]   = tok;
        validf[j][t] = v;
        coeff[j][t]  = v / (float)(cnt > 1 ? cnt : 1);
        if (v != 0.0f && cnt > 0) atomicOr(&amask_sh, 1 << j);
    } else if (tid >= 320 && tid < 384) {
        const int lane = tid - 320;
        float s = maskf[lane] + maskf[lane + 64];
        for (int off = 32; off; off >>= 1) s += __shfl_xor(s, off, 64);
        if (lane == 0) inv_msum = 1.0f / fmaxf(s, 1.0f);
    }
    __syncthreads();

    // ---- Phase B2: fold 1/n_valid; build active-row list + slot map ----
    if (tid < NARG) {
        float nv = 0.0f;
        #pragma unroll
        for (int t = 0; t < TT; ++t) nv += validf[tid][t];
        const float inv = 1.0f / fmaxf(nv, 1.0f);
        #pragma unroll
        for (int t = 0; t < TT; ++t) coeff[tid][t] *= inv;
    } else if (tid == NARG) {
        int n = 0;
        const int m = amask_sh;
        for (int j = 0; j < NARG; ++j) {
            slotmap[j] = -1;
            if ((m >> j) & 1) actlist[n++] = j;
        }
        nact_sh = n;
        for (int s = n; s < NARG; ++s) actlist[s] = -1;
        for (int s = 0; s < n && s < 3; ++s) slotmap[actlist[s]] = s + 1;
    }
    __syncthreads();

    // ---- Phase C: slot-packed weights (threads 0..511) ----
    if (tid < LL * 4) {
        const int l = tid >> 2;
        const int s = tid & 3;
        float w = 0.0f;
        if (s == 0) {
            w = maskf[l] * inv_msum;
        } else {
            const int j = actlist[s - 1];
            if (j >= 0) {
                const int sl = sid[l];
                #pragma unroll
                for (int t = 0; t < TT; ++t)
                    w += (sl == toks[j][t]) ? coeff[j][t] : 0.0f;
            }
        }
        Wt4[l][s] = w;
    }
    __syncthreads();

    // ---- Phase D: each thread sweeps its 16-row segment, 4 cols ----
    const float* ep = emb_g + (size_t)bs * (LL * DD)
                    + (size_t)(seg * SEGL) * DD + colbase;

    float4 acc0 = make_float4(0.f, 0.f, 0.f, 0.f);
    float4 acc1 = acc0, acc2 = acc0, acc3 = acc0;
    {
        float4 cur[CH], nxt[CH];
        #pragma unroll
        for (int j = 0; j < CH; ++j)
            cur[j] = *reinterpret_cast<const float4*>(&ep[(size_t)j * DD]);
        #pragma unroll
        for (int l0 = 0; l0 < SEGL; l0 += CH) {
            if (l0 + CH < SEGL) {
                #pragma unroll
                for (int j = 0; j < CH; ++j)
                    nxt[j] = *reinterpret_cast<const float4*>(&ep[(size_t)(l0 + CH + j) * DD]);
            }
            #pragma unroll
            for (int j = 0; j < CH; ++j) {
                const float4 w = *reinterpret_cast<const float4*>(&Wt4[seg * SEGL + l0 + j][0]);
                const float4 e = cur[j];
                acc0.x += w.x * e.x; acc0.y += w.x * e.y; acc0.z += w.x * e.z; acc0.w += w.x * e.w;
                acc1.x += w.y * e.x; acc1.y += w.y * e.y; acc1.z += w.y * e.z; acc1.w += w.y * e.w;
                acc2.x += w.z * e.x; acc2.y += w.z * e.y; acc2.z += w.z * e.z; acc2.w += w.z * e.w;
                acc3.x += w.w * e.x; acc3.y += w.w * e.y; acc3.z += w.w * e.z; acc3.w += w.w * e.w;
            }
            #pragma unroll
            for (int j = 0; j < CH; ++j) cur[j] = nxt[j];
        }
    }
    P4[seg][q][0] = acc0;
    P4[seg][q][1] = acc1;
    P4[seg][q][2] = acc2;
    P4[seg][q][3] = acc3;
    __syncthreads();

    // ---- Combine across segments; store all 25 rows (zeros for inactive) ----
    {
        const int g = seg;              // 0..7
        #pragma unroll
        for (int i = 0; i < 4; ++i) {
            const int r = g + 8 * i;    // rows 0..24 covered, <=4 per thread-group
            if (r >= 25) break;
            float4 val = make_float4(0.f, 0.f, 0.f, 0.f);
            int s = -1;
            if (r == 0) s = 0;
            else if (slotmap[r - 1] >= 0) s = slotmap[r - 1];
            if (s >= 0) {
                #pragma unroll
                for (int g2 = 0; g2 < NSEG; ++g2) {
                    const float4 p = P4[g2][q][s];
                    val.x += p.x; val.y += p.y; val.z += p.z; val.w += p.w;
                }
            }
            if (r == 0) {
                *reinterpret_cast<float4*>(&out0[(size_t)bs * DD + colbase]) = val;
            } else {
                const int j = r - 1;
                *reinterpret_cast<float4*>(
                    &outA[(size_t)(j >> 3) * (BB * SS * AA * DD) +
                          ((size_t)bs * AA + (j & 7)) * DD + colbase]) = val;
            }
        }
    }

    // ---- Rare: more than 3 active rows -> extra block-uniform sweeps ----
    for (int e = 3; e < nact_sh; ++e) {
        const int je = actlist[e];
        __syncthreads();
        if (tid < LL) {
            const int sl = sid[tid];
            float w = 0.0f;
            #pragma unroll
            for (int t = 0; t < TT; ++t)
                w += (sl == toks[je][t]) ? coeff[je][t] : 0.0f;
            Wx[tid] = w;
        }
        __syncthreads();
        float4 acc = make_float4(0.f, 0.f, 0.f, 0.f);
        for (int l = 0; l < SEGL; ++l) {
            const float w = Wx[seg * SEGL + l];
            const float4 ev = *reinterpret_cast<const float4*>(&ep[(size_t)l * DD]);
            acc.x += w * ev.x; acc.y += w * ev.y; acc.z += w * ev.z; acc.w += w * ev.w;
        }
        P4[seg][q][0] = acc;
        __syncthreads();
        if (seg == 0) {
            float4 s = make_float4(0.f, 0.f, 0.f, 0.f);
            #pragma unroll
            for (int g2 = 0; g2 < NSEG; ++g2) {
                const float4 p = P4[g2][q][0];
                s.x += p.x; s.y += p.y; s.z += p.z; s.w += p.w;
            }
            *reinterpret_cast<float4*>(
                &outA[(size_t)(je >> 3) * (BB * SS * AA * DD) +
                      ((size_t)bs * AA + (je & 7)) * DD + colbase]) = s;
        }
    }
}

extern "C" void kernel_launch(void* const* d_in, const int* in_sizes, int n_in,
                              void* d_out, int out_size, void* d_ws, size_t ws_size,
                              hipStream_t stream) {
    const int*   sid  = (const int*)d_in[0];
    const int*   mask = (const int*)d_in[1];
    const float* emb  = (const float*)d_in[2];
    const int*   pred = (const int*)d_in[3];
    const int*   a0   = (const int*)d_in[4];
    const int*   a1   = (const int*)d_in[5];
    float* outp = (float*)d_out;

    srl_kernel<<<dim3(BB * SS, DD / COLS), dim3(NT), 0, stream>>>(
        sid, mask, emb, pred, a0, a1, outp);
}

// Round 9
// 28.981 us; speedup vs baseline: 2.4983x; 1.0588x over previous
//
#include <hip/hip_runtime.h>

#define BB 16
#define SS 16
#define LL 128
#define DD 768
#define AA 8
#define TT 8
#define PAD_ID 1
#define NARG 24          // 3 arg types * 8 args
#define NT 768           // 12 waves
#define NQ 96            // float4 col-quads per block (384 cols)
#define NSEG 8           // in-block L split
#define SEGL 16          // LL / NSEG
#define CH 8             // rows per pipeline stage (SEGL = 2*CH)
#define COLS 384         // cols per block

__global__ __launch_bounds__(NT) void srl_kernel(
    const int* __restrict__ sid_g,
    const int* __restrict__ mask_g,
    const float* __restrict__ emb_g,
    const int* __restrict__ pred_g,
    const int* __restrict__ a0_g,
    const int* __restrict__ a1_g,
    float* __restrict__ out)
{
    __shared__ int    sid[LL];
    __shared__ float  maskf[LL];
    __shared__ float  Wt4[LL][4];       // slot-packed weights (slot0 = mean row)
    __shared__ float  coeff[NARG][TT];
    __shared__ float  validf[NARG][TT];
    __shared__ int    toks[NARG][TT];
    __shared__ float  inv_msum;
    __shared__ int    amask_sh;
    __shared__ int    nact_sh;
    __shared__ int    actlist[NARG];
    __shared__ int    slotmap[NARG];    // row j -> slot 1..3, or -1
    __shared__ float4 P4[NSEG][NQ][4];  // cross-segment partials (48 KB)
    __shared__ float  Wx[LL];           // weights for rare extra rows

    const int bs  = blockIdx.x;
    const int cc  = blockIdx.y;
    const int tid = threadIdx.x;
    const int q   = tid % NQ;           // col-quad within block
    const int seg = tid / NQ;           // 0..7

    float* out0 = out;                               // [B*S, D]
    float* outA = out + (size_t)BB * SS * DD;        // 3 x [B*S, A, D]
    const int colbase = cc * COLS + 4 * q;

    // ---- Early prefetch: issue first chunk's E loads BEFORE setup so their
    //      HBM latency hides under phases A-C ----
    const float* ep = emb_g + (size_t)bs * (LL * DD)
                    + (size_t)(seg * SEGL) * DD + colbase;
    float4 cur[CH], nxt[CH];
    #pragma unroll
    for (int j = 0; j < CH; ++j)
        cur[j] = *reinterpret_cast<const float4*>(&ep[(size_t)j * DD]);

    // ---- Phase A: stage sentence ids + mask ----
    if (tid < LL) {
        sid[tid]   = sid_g[bs * LL + tid];
        maskf[tid] = (float)mask_g[bs * LL + tid];
    }
    if (tid == 0) amask_sh = 0;
    __syncthreads();

    // ---- Phase B1: per-token match count + valid (threads 0..191),
    //      mask-sum on threads 320..383 ----
    if (tid < NARG * TT) {
        const int j = tid >> 3;
        const int t = tid & 7;
        const int k = j >> 3;
        const int a = j & 7;
        const int* src = (k == 0) ? pred_g : (k == 1) ? a0_g : a1_g;
        const int tok = src[bs * AA * TT + a * TT + t];
        int cnt = 0;
        for (int l = 0; l < LL; ++l) cnt += (sid[l] == tok) ? 1 : 0;
        const float v = (tok != PAD_ID) ? 1.0f : 0.0f;
        toks[j][t]   = tok;
        validf[j][t] = v;
        coeff[j][t]  = v / (float)(cnt > 1 ? cnt : 1);
        if (v != 0.0f && cnt > 0) atomicOr(&amask_sh, 1 << j);
    } else if (tid >= 320 && tid < 384) {
        const int lane = tid - 320;
        float s = maskf[lane] + maskf[lane + 64];
        for (int off = 32; off; off >>= 1) s += __shfl_xor(s, off, 64);
        if (lane == 0) inv_msum = 1.0f / fmaxf(s, 1.0f);
    }
    __syncthreads();

    // ---- Phase B2: fold 1/n_valid; build active-row list + slot map ----
    if (tid < NARG) {
        float nv = 0.0f;
        #pragma unroll
        for (int t = 0; t < TT; ++t) nv += validf[tid][t];
        const float inv = 1.0f / fmaxf(nv, 1.0f);
        #pragma unroll
        for (int t = 0; t < TT; ++t) coeff[tid][t] *= inv;
    } else if (tid == NARG) {
        int n = 0;
        const int m = amask_sh;
        for (int j = 0; j < NARG; ++j) {
            slotmap[j] = -1;
            if ((m >> j) & 1) actlist[n++] = j;
        }
        nact_sh = n;
        for (int s = n; s < NARG; ++s) actlist[s] = -1;
        for (int s = 0; s < n && s < 3; ++s) slotmap[actlist[s]] = s + 1;
    }
    __syncthreads();

    // ---- Phase C: slot-packed weights (threads 0..511) ----
    if (tid < LL * 4) {
        const int l = tid >> 2;
        const int s = tid & 3;
        float w = 0.0f;
        if (s == 0) {
            w = maskf[l] * inv_msum;
        } else {
            const int j = actlist[s - 1];
            if (j >= 0) {
                const int sl = sid[l];
                #pragma unroll
                for (int t = 0; t < TT; ++t)
                    w += (sl == toks[j][t]) ? coeff[j][t] : 0.0f;
            }
        }
        Wt4[l][s] = w;
    }
    __syncthreads();

    // ---- Phase D: each thread sweeps its 16-row segment, 4 cols ----
    float4 acc0 = make_float4(0.f, 0.f, 0.f, 0.f);
    float4 acc1 = acc0, acc2 = acc0, acc3 = acc0;
    {
        #pragma unroll
        for (int l0 = 0; l0 < SEGL; l0 += CH) {
            if (l0 + CH < SEGL) {
                #pragma unroll
                for (int j = 0; j < CH; ++j)
                    nxt[j] = *reinterpret_cast<const float4*>(&ep[(size_t)(l0 + CH + j) * DD]);
            }
            #pragma unroll
            for (int j = 0; j < CH; ++j) {
                const float4 w = *reinterpret_cast<const float4*>(&Wt4[seg * SEGL + l0 + j][0]);
                const float4 e = cur[j];
                acc0.x += w.x * e.x; acc0.y += w.x * e.y; acc0.z += w.x * e.z; acc0.w += w.x * e.w;
                acc1.x += w.y * e.x; acc1.y += w.y * e.y; acc1.z += w.y * e.z; acc1.w += w.y * e.w;
                acc2.x += w.z * e.x; acc2.y += w.z * e.y; acc2.z += w.z * e.z; acc2.w += w.z * e.w;
                acc3.x += w.w * e.x; acc3.y += w.w * e.y; acc3.z += w.w * e.z; acc3.w += w.w * e.w;
            }
            #pragma unroll
            for (int j = 0; j < CH; ++j) cur[j] = nxt[j];
        }
    }
    P4[seg][q][0] = acc0;
    P4[seg][q][1] = acc1;
    P4[seg][q][2] = acc2;
    P4[seg][q][3] = acc3;
    __syncthreads();

    // ---- Combine across segments; store all 25 rows (zeros for inactive) ----
    {
        const int g = seg;              // 0..7
        #pragma unroll
        for (int i = 0; i < 4; ++i) {
            const int r = g + 8 * i;    // rows 0..24 covered
            if (r >= 25) break;
            float4 val = make_float4(0.f, 0.f, 0.f, 0.f);
            int s = -1;
            if (r == 0) s = 0;
            else if (slotmap[r - 1] >= 0) s = slotmap[r - 1];
            if (s >= 0) {
                #pragma unroll
                for (int g2 = 0; g2 < NSEG; ++g2) {
                    const float4 p = P4[g2][q][s];
                    val.x += p.x; val.y += p.y; val.z += p.z; val.w += p.w;
                }
            }
            if (r == 0) {
                *reinterpret_cast<float4*>(&out0[(size_t)bs * DD + colbase]) = val;
            } else {
                const int j = r - 1;
                *reinterpret_cast<float4*>(
                    &outA[(size_t)(j >> 3) * (BB * SS * AA * DD) +
                          ((size_t)bs * AA + (j & 7)) * DD + colbase]) = val;
            }
        }
    }

    // ---- Rare: more than 3 active rows -> extra block-uniform sweeps ----
    for (int e = 3; e < nact_sh; ++e) {
        const int je = actlist[e];
        __syncthreads();
        if (tid < LL) {
            const int sl = sid[tid];
            float w = 0.0f;
            #pragma unroll
            for (int t = 0; t < TT; ++t)
                w += (sl == toks[je][t]) ? coeff[je][t] : 0.0f;
            Wx[tid] = w;
        }
        __syncthreads();
        float4 acc = make_float4(0.f, 0.f, 0.f, 0.f);
        for (int l = 0; l < SEGL; ++l) {
            const float w = Wx[seg * SEGL + l];
            const float4 ev = *reinterpret_cast<const float4*>(&ep[(size_t)l * DD]);
            acc.x += w * ev.x; acc.y += w * ev.y; acc.z += w * ev.z; acc.w += w * ev.w;
        }
        P4[seg][q][0] = acc;
        __syncthreads();
        if (seg == 0) {
            float4 s = make_float4(0.f, 0.f, 0.f, 0.f);
            #pragma unroll
            for (int g2 = 0; g2 < NSEG; ++g2) {
                const float4 p = P4[g2][q][0];
                s.x += p.x; s.y += p.y; s.z += p.z; s.w += p.w;
            }
            *reinterpret_cast<float4*>(
                &outA[(size_t)(je >> 3) * (BB * SS * AA * DD) +
                      ((size_t)bs * AA + (je & 7)) * DD + colbase]) = s;
        }
    }
}

extern "C" void kernel_launch(void* const* d_in, const int* in_sizes, int n_in,
                              void* d_out, int out_size, void* d_ws, size_t ws_size,
                              hipStream_t stream) {
    const int*   sid  = (const int*)d_in[0];
    const int*   mask = (const int*)d_in[1];
    const float* emb  = (const float*)d_in[2];
    const int*   pred = (const int*)d_in[3];
    const int*   a0   = (const int*)d_in[4];
    const int*   a1   = (const int*)d_in[5];
    float* outp = (float*)d_out;

    srl_kernel<<<dim3(BB * SS, DD / COLS), dim3(NT), 0, stream>>>(
        sid, mask, emb, pred, a0, a1, outp);
}